// Round 6
// baseline (334.689 us; speedup 1.0000x reference)
//
#include <hip/hip_runtime.h>
#include <hip/hip_bf16.h>

typedef __bf16 bf16_t;
typedef __bf16 bf16x4 __attribute__((ext_vector_type(4)));
typedef __bf16 bf16x8 __attribute__((ext_vector_type(8)));
typedef float floatx4 __attribute__((ext_vector_type(4)));

#define N_NODES 4096
#define F_IN 128
#define NUM_HEADS 4
#define D_HID 64
#define F_OUT 256  // NUM_HEADS * D_HID
#define NEG_SLOPE 0.2f

// ---------------------------------------------------------------------------
// Kernel 1: projections (f32 in; GB bf16 fragment-linear; el/E1r/E2r f32).
//   GB: g[j][h*64+f] stored so a 16x16x32 MFMA B-fragment is contiguous 1 KB:
//   GB[h][j>>5][f>>4][lane=(f&15)+16*((j>>3)&3)][j&7].
//   el[h][j]  = <ga[j,h,:], w_attn[:32]>
//   E1r[h][j] = exp(<ga[j,h,:], w_attn[32:]>),  E2r[h][j] = exp(0.2*<...>)
// 1024 blocks x 384 threads; block handles 4 nodes.
// ---------------------------------------------------------------------------
__global__ __launch_bounds__(384) void proj_kernel(
    const float* __restrict__ hmat, const float* __restrict__ Wp,
    const float* __restrict__ Wa, const float* __restrict__ wattn,
    bf16_t* __restrict__ GB, float* __restrict__ el,
    float* __restrict__ E1r, float* __restrict__ E2r)
{
    __shared__ float hl[4][F_IN];
    const int t = threadIdx.x;
    const int j0 = blockIdx.x * 4;

    if (t < 128) {
        const int jl = t >> 5, m0 = (t & 31) * 4;
        *reinterpret_cast<float4*>(&hl[jl][m0]) =
            *reinterpret_cast<const float4*>(&hmat[(size_t)(j0 + jl) * F_IN + m0]);
    }
    __syncthreads();

    float acc[4] = {0.f, 0.f, 0.f, 0.f};

    const float* wptr;
    int stride;
    if (t < 256) { wptr = Wp + t;         stride = 256; }
    else         { wptr = Wa + (t - 256); stride = 128; }

    for (int m = 0; m < F_IN; m += 4) {
        const float w0 = wptr[(size_t)(m + 0) * stride];
        const float w1 = wptr[(size_t)(m + 1) * stride];
        const float w2 = wptr[(size_t)(m + 2) * stride];
        const float w3 = wptr[(size_t)(m + 3) * stride];
#pragma unroll
        for (int jl = 0; jl < 4; ++jl) {
            const float4 hv = *reinterpret_cast<const float4*>(&hl[jl][m]);
            acc[jl] = fmaf(hv.w, w3, fmaf(hv.z, w2, fmaf(hv.y, w1, fmaf(hv.x, w0, acc[jl]))));
        }
    }

    if (t < 256) {
        const int h = t >> 6, f = t & 63;
        bf16x4 o;
#pragma unroll
        for (int q = 0; q < 4; ++q) o[q] = (bf16_t)acc[q];
        const size_t base = ((((size_t)h * 128 + (j0 >> 5)) * 4 + (f >> 4)) * 64
                             + (f & 15) + 16 * ((j0 >> 3) & 3)) * 8 + (j0 & 7);
        *reinterpret_cast<bf16x4*>(&GB[base]) = o;
    } else {
        const int ta = t - 256;          // waves 4,5; 32-lane group per head
        const int ha = ta >> 5, k = ta & 31;
        const float wl = wattn[k], wr = wattn[32 + k];
#pragma unroll
        for (int jl = 0; jl < 4; ++jl) {
            float vl = acc[jl] * wl;
            float vr = acc[jl] * wr;
#pragma unroll
            for (int s = 16; s >= 1; s >>= 1) {
                vl += __shfl_xor(vl, s, 64);
                vr += __shfl_xor(vr, s, 64);
            }
            if (k == 0) {
                el[ha * N_NODES + j0 + jl]  = vl;
                E1r[ha * N_NODES + j0 + jl] = __expf(vr);
                E2r[ha * N_NODES + j0 + jl] = __expf(NEG_SLOPE * vr);
            }
        }
    }
}

// ---------------------------------------------------------------------------
// Kernel 2: LDS-tiled fused attention, exp-free hot loop.
// Grid (128 i-tiles of 32 rows, njc) x 512 threads = 8 waves; 2 blocks/CU.
// p_ij = mask * (el+er>0 ? E1i*E1r[j] : E2i*E2r[j]); sign test via
// E1r[j] > exp(-el). Phase 1 writes bf16 P (XOR-swizzled) to LDS from
// coalesced adj loads; phase 2 runs MFMA on P_s x GB_s (fragment-linear
// staged tile), denominator via all-ones B-fragment MFMA (C-layout).
// Static LDS = 16 KB (P_s) + 32 KB (GB_s) = 48 KB.
// ---------------------------------------------------------------------------
__global__ __launch_bounds__(512) void attn_kernel(
    const float* __restrict__ adj, const bf16_t* __restrict__ GB,
    const float* __restrict__ el, const float* __restrict__ E1r,
    const float* __restrict__ E2r,
    float* __restrict__ numout, float* __restrict__ den_g,
    int njc, int ntiles)
{
    __shared__ bf16_t P_s[NUM_HEADS * 32 * 64];   // 16 KiB
    __shared__ bf16_t GB_s[32 * 512];             // 32 KiB (32 subs x 1 KB)

    const int tid = threadIdx.x;
    const int i0  = blockIdx.x * 32;
    const int jc  = blockIdx.y;
    const int jT0 = jc * ntiles * 64;

    // phase-1 identity: thread -> (block-local i, tile-local j*4)
    const int pi   = tid >> 4;            // 0..31
    const int pj4  = (tid & 15) << 2;     // 0,4,..,60
    const int glog = pj4 >> 3;
    const int goff = pj4 & 7;
    const int psw  = ((glog ^ (pi & 7)) << 3) + goff;

    // phase-2 identity
    const int wave = tid >> 6;            // 0..7
    const int hh   = wave >> 1;           // head
    const int mt   = wave & 1;            // m-tile (16 rows)
    const int lane = tid & 63;
    const int m    = lane & 15;
    const int quad = lane >> 4;

    // per-thread i-side exponential factors (4 heads)
    float E1i[NUM_HEADS], E2i[NUM_HEADS], Ti[NUM_HEADS];
#pragma unroll
    for (int h = 0; h < NUM_HEADS; ++h) {
        const float e = el[h * N_NODES + i0 + pi];
        E1i[h] = __expf(e);
        E2i[h] = __expf(NEG_SLOPE * e);
        Ti[h]  = __expf(-e);
    }

    const float* adjp = adj + (size_t)(i0 + pi) * N_NODES + pj4;

    // GB staging: wave stages subs s=wave*4..wave*4+3; s=(jbL*16? no:) s -> (jbL=s>>4, h=(s>>2)&3, fg=s&3)
    int sh[4], sf[4], sj[4];
#pragma unroll
    for (int ss = 0; ss < 4; ++ss) {
        const int s = wave * 4 + ss;
        sh[ss] = (s >> 2) & 3; sf[ss] = s & 3; sj[ss] = s >> 4;
    }

    floatx4 acc0 = {0.f, 0.f, 0.f, 0.f};
    floatx4 acc1 = acc0, acc2 = acc0, acc3 = acc0, accd = acc0;
    bf16x8 ones;
#pragma unroll
    for (int q = 0; q < 8; ++q) ones[q] = (bf16_t)1.0f;

    // prologue: prefetch tile 0 into registers
    const int jb32 = jT0 >> 5;
    float4 adjv = *reinterpret_cast<const float4*>(adjp + jT0);
    float4 gbv[4];
#pragma unroll
    for (int ss = 0; ss < 4; ++ss)
        gbv[ss] = *reinterpret_cast<const float4*>(
            GB + ((size_t)(sh[ss] * 128 + jb32 + sj[ss]) * 4 + sf[ss]) * 512 + lane * 8);

    for (int k = 0; k < ntiles; ++k) {
        const int jT = jT0 + k * 64;
        // ---------- phase 1 ----------
#pragma unroll
        for (int ss = 0; ss < 4; ++ss)
            *reinterpret_cast<float4*>(&GB_s[(wave * 4 + ss) * 512 + lane * 8]) = gbv[ss];

        float4 adjn, gbn[4];
        if (k + 1 < ntiles) {
            const int jbn = (jT + 64) >> 5;
            adjn = *reinterpret_cast<const float4*>(adjp + jT + 64);
#pragma unroll
            for (int ss = 0; ss < 4; ++ss)
                gbn[ss] = *reinterpret_cast<const float4*>(
                    GB + ((size_t)(sh[ss] * 128 + jbn + sj[ss]) * 4 + sf[ss]) * 512 + lane * 8);
        }

        const bool k0 = adjv.x >= 0.5f, k1 = adjv.y >= 0.5f,
                   k2 = adjv.z >= 0.5f, k3 = adjv.w >= 0.5f;
#pragma unroll
        for (int h = 0; h < NUM_HEADS; ++h) {
            const float4 a1 = *reinterpret_cast<const float4*>(E1r + h * N_NODES + jT + pj4);
            const float4 a2 = *reinterpret_cast<const float4*>(E2r + h * N_NODES + jT + pj4);
            const float p0 = (a1.x > Ti[h]) ? E1i[h] * a1.x : E2i[h] * a2.x;
            const float p1 = (a1.y > Ti[h]) ? E1i[h] * a1.y : E2i[h] * a2.y;
            const float p2 = (a1.z > Ti[h]) ? E1i[h] * a1.z : E2i[h] * a2.z;
            const float p3 = (a1.w > Ti[h]) ? E1i[h] * a1.w : E2i[h] * a2.w;
            bf16x4 pv;
            pv[0] = (bf16_t)(k0 ? p0 : 0.f);
            pv[1] = (bf16_t)(k1 ? p1 : 0.f);
            pv[2] = (bf16_t)(k2 ? p2 : 0.f);
            pv[3] = (bf16_t)(k3 ? p3 : 0.f);
            *reinterpret_cast<bf16x4*>(&P_s[(h * 32 + pi) * 64 + psw]) = pv;
        }
        __syncthreads();   // P_s + GB_s ready
        // ---------- phase 2 ----------
#pragma unroll
        for (int kt = 0; kt < 2; ++kt) {
            const int gphys = (((kt * 4 + quad) ^ (m & 7)) << 3);
            const bf16x8 af = *reinterpret_cast<const bf16x8*>(
                &P_s[(hh * 32 + mt * 16 + m) * 64 + gphys]);
            accd = __builtin_amdgcn_mfma_f32_16x16x32_bf16(af, ones, accd, 0, 0, 0);
            const int bb = (kt * 16 + hh * 4) * 512 + lane * 8;
            const bf16x8 b0 = *reinterpret_cast<const bf16x8*>(&GB_s[bb]);
            const bf16x8 b1 = *reinterpret_cast<const bf16x8*>(&GB_s[bb + 512]);
            const bf16x8 b2 = *reinterpret_cast<const bf16x8*>(&GB_s[bb + 1024]);
            const bf16x8 b3 = *reinterpret_cast<const bf16x8*>(&GB_s[bb + 1536]);
            acc0 = __builtin_amdgcn_mfma_f32_16x16x32_bf16(af, b0, acc0, 0, 0, 0);
            acc1 = __builtin_amdgcn_mfma_f32_16x16x32_bf16(af, b1, acc1, 0, 0, 0);
            acc2 = __builtin_amdgcn_mfma_f32_16x16x32_bf16(af, b2, acc2, 0, 0, 0);
            acc3 = __builtin_amdgcn_mfma_f32_16x16x32_bf16(af, b3, acc3, 0, 0, 0);
        }
        if (k + 1 < ntiles) {
            adjv = adjn;
#pragma unroll
            for (int ss = 0; ss < 4; ++ss) gbv[ss] = gbn[ss];
        }
        __syncthreads();   // tile consumed
    }

    // epilogue: C/D row = mt*16 + quad*4 + r, col = m; den in accd[r]
    const int ibase = i0 + mt * 16 + quad * 4;
    if (njc == 1) {
#pragma unroll
        for (int r = 0; r < 4; ++r) {
            const float rd = 1.0f / accd[r];
            float* dst = numout + (size_t)(ibase + r) * F_OUT + hh * D_HID + m;
            dst[0]  = acc0[r] * rd;
            dst[16] = acc1[r] * rd;
            dst[32] = acc2[r] * rd;
            dst[48] = acc3[r] * rd;
        }
    } else {
        float* nrow = numout + (size_t)jc * ((size_t)N_NODES * F_OUT);
#pragma unroll
        for (int r = 0; r < 4; ++r) {
            float* dst = nrow + (size_t)(ibase + r) * F_OUT + hh * D_HID + m;
            dst[0]  = acc0[r];
            dst[16] = acc1[r];
            dst[32] = acc2[r];
            dst[48] = acc3[r];
        }
        if (m == 0) {
#pragma unroll
            for (int r = 0; r < 4; ++r)
                den_g[((size_t)jc * N_NODES + ibase + r) * NUM_HEADS + hh] = accd[r];
        }
    }
}

// ---------------------------------------------------------------------------
// Kernel 3 (njc>1): sum chunk partials, divide, store f32.
// ---------------------------------------------------------------------------
__global__ __launch_bounds__(256) void reduce_kernel(
    const float* __restrict__ num, const float* __restrict__ den,
    float* __restrict__ out, int njc)
{
    const int idx = blockIdx.x * 256 + threadIdx.x;
    const int i  = idx >> 8;
    const int c  = idx & 255;
    const int hh = c >> 6;
    float n = 0.f, d = 0.f;
    for (int jc = 0; jc < njc; ++jc) {
        n += num[(size_t)jc * ((size_t)N_NODES * F_OUT) + idx];
        d += den[((size_t)jc * N_NODES + i) * NUM_HEADS + hh];
    }
    out[idx] = n / d;
}

// ---------------------------------------------------------------------------
extern "C" void kernel_launch(void* const* d_in, const int* in_sizes, int n_in,
                              void* d_out, int out_size, void* d_ws, size_t ws_size,
                              hipStream_t stream)
{
    const float* hmat = (const float*)d_in[0];   // (4096, 128) f32
    const float* adj  = (const float*)d_in[1];   // (4096, 4096) f32
    const float* Wp   = (const float*)d_in[2];   // (128, 256) f32
    const float* Wa   = (const float*)d_in[3];   // (128, 128) f32
    const float* watt = (const float*)d_in[4];   // (64,) f32
    float* out = (float*)d_out;                  // (4096, 256) f32

    char* ws = (char*)d_ws;
    bf16_t* GB  = (bf16_t*)ws;                                   // 2 MiB
    float*  el  = (float*)(ws + (2ull << 20));                   // 64 KiB
    float*  E1r = (float*)(ws + (2ull << 20) + (64ull << 10));   // 64 KiB
    float*  E2r = (float*)(ws + (2ull << 20) + (128ull << 10));  // 64 KiB
    const size_t baseoff = (2ull << 20) + (192ull << 10);

    const size_t num_bytes = (size_t)N_NODES * F_OUT * 4;        // 4 MiB per chunk
    const size_t den_bytes = (size_t)N_NODES * NUM_HEADS * 4;    // 64 KiB per chunk
    const int njc = (ws_size >= baseoff + 4 * (num_bytes + den_bytes)) ? 4 : 2;

    float* num = (float*)(ws + baseoff);
    float* den = (float*)(ws + baseoff + (size_t)njc * num_bytes);

    proj_kernel<<<1024, 384, 0, stream>>>(hmat, Wp, Wa, watt, GB, el, E1r, E2r);
    attn_kernel<<<dim3(128, njc), 512, 0, stream>>>(adj, GB, el, E1r, E2r,
                                                    num, den, njc, (N_NODES / njc) / 64);
    reduce_kernel<<<(N_NODES * F_OUT) / 256, 256, 0, stream>>>(num, den, out, njc);
}

// Round 7
// 166.440 us; speedup vs baseline: 2.0109x; 2.0109x over previous
//
#include <hip/hip_runtime.h>
#include <hip/hip_bf16.h>

typedef __bf16 bf16_t;
typedef __bf16 bf16x4 __attribute__((ext_vector_type(4)));
typedef __bf16 bf16x8 __attribute__((ext_vector_type(8)));
typedef float floatx4 __attribute__((ext_vector_type(4)));

#define N_NODES 4096
#define F_IN 128
#define NUM_HEADS 4
#define D_HID 64
#define F_OUT 256  // NUM_HEADS * D_HID
#define NEG_SLOPE 0.2f

// ---------------------------------------------------------------------------
// Kernel 1: projections (f32 in; GB bf16 fragment-linear; el/E1r/E2r f32).
//   GB: g[j][h*64+f] stored so a 16x16x32 MFMA B-fragment is contiguous 1 KB:
//   GB[h][j>>5][f>>4][lane=(f&15)+16*((j>>3)&3)][j&7].
//   el[h][j]  = <ga[j,h,:], w_attn[:32]>
//   E1r[h][j] = exp(<ga[j,h,:], w_attn[32:]>),  E2r[h][j] = exp(0.2*<...>)
// 1024 blocks x 384 threads; block handles 4 nodes.
// ---------------------------------------------------------------------------
__global__ __launch_bounds__(384) void proj_kernel(
    const float* __restrict__ hmat, const float* __restrict__ Wp,
    const float* __restrict__ Wa, const float* __restrict__ wattn,
    bf16_t* __restrict__ GB, float* __restrict__ el,
    float* __restrict__ E1r, float* __restrict__ E2r)
{
    __shared__ float hl[4][F_IN];
    const int t = threadIdx.x;
    const int j0 = blockIdx.x * 4;

    if (t < 128) {
        const int jl = t >> 5, m0 = (t & 31) * 4;
        *reinterpret_cast<float4*>(&hl[jl][m0]) =
            *reinterpret_cast<const float4*>(&hmat[(size_t)(j0 + jl) * F_IN + m0]);
    }
    __syncthreads();

    float acc[4] = {0.f, 0.f, 0.f, 0.f};

    const float* wptr;
    int stride;
    if (t < 256) { wptr = Wp + t;         stride = 256; }
    else         { wptr = Wa + (t - 256); stride = 128; }

    for (int m = 0; m < F_IN; m += 4) {
        const float w0 = wptr[(size_t)(m + 0) * stride];
        const float w1 = wptr[(size_t)(m + 1) * stride];
        const float w2 = wptr[(size_t)(m + 2) * stride];
        const float w3 = wptr[(size_t)(m + 3) * stride];
#pragma unroll
        for (int jl = 0; jl < 4; ++jl) {
            const float4 hv = *reinterpret_cast<const float4*>(&hl[jl][m]);
            acc[jl] = fmaf(hv.w, w3, fmaf(hv.z, w2, fmaf(hv.y, w1, fmaf(hv.x, w0, acc[jl]))));
        }
    }

    if (t < 256) {
        const int h = t >> 6, f = t & 63;
        bf16x4 o;
#pragma unroll
        for (int q = 0; q < 4; ++q) o[q] = (bf16_t)acc[q];
        const size_t base = ((((size_t)h * 128 + (j0 >> 5)) * 4 + (f >> 4)) * 64
                             + (f & 15) + 16 * ((j0 >> 3) & 3)) * 8 + (j0 & 7);
        *reinterpret_cast<bf16x4*>(&GB[base]) = o;
    } else {
        const int ta = t - 256;          // waves 4,5; 32-lane group per head
        const int ha = ta >> 5, k = ta & 31;
        const float wl = wattn[k], wr = wattn[32 + k];
#pragma unroll
        for (int jl = 0; jl < 4; ++jl) {
            float vl = acc[jl] * wl;
            float vr = acc[jl] * wr;
#pragma unroll
            for (int s = 16; s >= 1; s >>= 1) {
                vl += __shfl_xor(vl, s, 64);
                vr += __shfl_xor(vr, s, 64);
            }
            if (k == 0) {
                el[ha * N_NODES + j0 + jl]  = vl;
                E1r[ha * N_NODES + j0 + jl] = __expf(vr);
                E2r[ha * N_NODES + j0 + jl] = __expf(NEG_SLOPE * vr);
            }
        }
    }
}

// ---------------------------------------------------------------------------
// Kernel 2: LDS-tiled fused attention; exp-free hot loop; single barrier per
// tile via double-buffered LDS. Grid (64 i-tiles of 64 rows, njc) x 1024 thr.
// Iter k: stage GB(k)+compute P(k) into buf, prefetch tile k+1 to regs,
// MFMA tile k-1 from buf^1, one __syncthreads. VALU (P) and MFMA phases touch
// different buffers -> interleave freely. LDS = 2*32 (P) + 2*32 (GB) = 128 KB.
// __launch_bounds__(1024,4): 128-VGPR cap, 1 block/CU (R6 spilled at 48).
// ---------------------------------------------------------------------------
__global__ __launch_bounds__(1024, 4) void attn_kernel(
    const float* __restrict__ adj, const bf16_t* __restrict__ GB,
    const float* __restrict__ el, const float* __restrict__ E1r,
    const float* __restrict__ E2r,
    float* __restrict__ numout, float* __restrict__ den_g,
    int njc, int ntiles)
{
    __shared__ bf16_t P_s[2][NUM_HEADS * 64 * 64];   // 2 x 32 KiB
    __shared__ bf16_t GB_s[2][32 * 512];             // 2 x 32 KiB

    const int tid = threadIdx.x;
    const int i0  = blockIdx.x * 64;
    const int jc  = blockIdx.y;
    const int jT0 = jc * ntiles * 64;

    // phase-1 identity: thread -> (block-local i, tile-local j*4)
    const int pi   = tid >> 4;            // 0..63
    const int pj4  = (tid & 15) << 2;     // 0,4,..,60
    const int glog = pj4 >> 3;
    const int goff = pj4 & 7;
    const int psw  = ((glog ^ (pi & 7)) << 3) + goff;

    // phase-2 identity
    const int wave = tid >> 6;            // 0..15
    const int hh   = wave >> 2;           // head
    const int mt   = wave & 3;            // m-tile (16 rows)
    const int lane = tid & 63;
    const int m    = lane & 15;
    const int quad = lane >> 4;

    // per-thread i-side exponential factors (4 heads)
    float E1i[NUM_HEADS], E2i[NUM_HEADS], Ti[NUM_HEADS];
#pragma unroll
    for (int h = 0; h < NUM_HEADS; ++h) {
        const float e = el[h * N_NODES + i0 + pi];
        E1i[h] = __expf(e);
        E2i[h] = __expf(NEG_SLOPE * e);
        Ti[h]  = __expf(-e);
    }

    const float* adjp = adj + (size_t)(i0 + pi) * N_NODES + pj4;

    // GB staging: wave stages subs s0,s1; sub s -> (jbL=s>>4, h=(s>>2)&3, fg=s&3)
    const int s0 = wave * 2, s1 = s0 + 1;
    const int s0h = (s0 >> 2) & 3, s0f = s0 & 3, s0j = s0 >> 4;
    const int s1h = (s1 >> 2) & 3, s1f = s1 & 3, s1j = s1 >> 4;

    floatx4 acc0 = {0.f, 0.f, 0.f, 0.f};
    floatx4 acc1 = acc0, acc2 = acc0, acc3 = acc0, accd = acc0;
    bf16x8 ones;
#pragma unroll
    for (int q = 0; q < 8; ++q) ones[q] = (bf16_t)1.0f;

    auto do_mfma = [&](int b) {
#pragma unroll
        for (int kt = 0; kt < 2; ++kt) {
            const int gphys = (((kt * 4 + quad) ^ (m & 7)) << 3);
            const bf16x8 af = *reinterpret_cast<const bf16x8*>(
                &P_s[b][(hh * 64 + mt * 16 + m) * 64 + gphys]);
            accd = __builtin_amdgcn_mfma_f32_16x16x32_bf16(af, ones, accd, 0, 0, 0);
            const int bb = (kt * 16 + hh * 4) * 512 + lane * 8;
            const bf16x8 b0 = *reinterpret_cast<const bf16x8*>(&GB_s[b][bb]);
            const bf16x8 b1 = *reinterpret_cast<const bf16x8*>(&GB_s[b][bb + 512]);
            const bf16x8 b2 = *reinterpret_cast<const bf16x8*>(&GB_s[b][bb + 1024]);
            const bf16x8 b3 = *reinterpret_cast<const bf16x8*>(&GB_s[b][bb + 1536]);
            acc0 = __builtin_amdgcn_mfma_f32_16x16x32_bf16(af, b0, acc0, 0, 0, 0);
            acc1 = __builtin_amdgcn_mfma_f32_16x16x32_bf16(af, b1, acc1, 0, 0, 0);
            acc2 = __builtin_amdgcn_mfma_f32_16x16x32_bf16(af, b2, acc2, 0, 0, 0);
            acc3 = __builtin_amdgcn_mfma_f32_16x16x32_bf16(af, b3, acc3, 0, 0, 0);
        }
    };

    // prologue: prefetch tile 0 into registers
    const int jb32 = jT0 >> 5;
    float4 adjv = *reinterpret_cast<const float4*>(adjp + jT0);
    float4 gbv0 = *reinterpret_cast<const float4*>(GB + ((size_t)(s0h * 128 + jb32 + s0j) * 4 + s0f) * 512 + lane * 8);
    float4 gbv1 = *reinterpret_cast<const float4*>(GB + ((size_t)(s1h * 128 + jb32 + s1j) * 4 + s1f) * 512 + lane * 8);

    int buf = 0;
    for (int k = 0; k < ntiles; ++k) {
        const int jT = jT0 + k * 64;
        // stage GB tile k (regs -> LDS[buf])
        *reinterpret_cast<float4*>(&GB_s[buf][s0 * 512 + lane * 8]) = gbv0;
        *reinterpret_cast<float4*>(&GB_s[buf][s1 * 512 + lane * 8]) = gbv1;

        // prefetch tile k+1 into registers
        float4 adjn, gbn0, gbn1;
        if (k + 1 < ntiles) {
            const int jbn = (jT + 64) >> 5;
            adjn = *reinterpret_cast<const float4*>(adjp + jT + 64);
            gbn0 = *reinterpret_cast<const float4*>(GB + ((size_t)(s0h * 128 + jbn + s0j) * 4 + s0f) * 512 + lane * 8);
            gbn1 = *reinterpret_cast<const float4*>(GB + ((size_t)(s1h * 128 + jbn + s1j) * 4 + s1f) * 512 + lane * 8);
        }

        // compute P tile k -> P_s[buf]  (exp-free: table factors)
        const bool k0 = adjv.x >= 0.5f, k1 = adjv.y >= 0.5f,
                   k2 = adjv.z >= 0.5f, k3 = adjv.w >= 0.5f;
#pragma unroll
        for (int h = 0; h < NUM_HEADS; ++h) {
            const float4 a1 = *reinterpret_cast<const float4*>(E1r + h * N_NODES + jT + pj4);
            const float4 a2 = *reinterpret_cast<const float4*>(E2r + h * N_NODES + jT + pj4);
            const float p0 = (a1.x > Ti[h]) ? E1i[h] * a1.x : E2i[h] * a2.x;
            const float p1 = (a1.y > Ti[h]) ? E1i[h] * a1.y : E2i[h] * a2.y;
            const float p2 = (a1.z > Ti[h]) ? E1i[h] * a1.z : E2i[h] * a2.z;
            const float p3 = (a1.w > Ti[h]) ? E1i[h] * a1.w : E2i[h] * a2.w;
            bf16x4 pv;
            pv[0] = (bf16_t)(k0 ? p0 : 0.f);
            pv[1] = (bf16_t)(k1 ? p1 : 0.f);
            pv[2] = (bf16_t)(k2 ? p2 : 0.f);
            pv[3] = (bf16_t)(k3 ? p3 : 0.f);
            *reinterpret_cast<bf16x4*>(&P_s[buf][(h * 64 + pi) * 64 + psw]) = pv;
        }

        // MFMA tile k-1 from the other buffer (independent of this iter's writes)
        if (k > 0) do_mfma(buf ^ 1);

        __syncthreads();   // publish tile k; retire reads of tile k-1

        if (k + 1 < ntiles) { adjv = adjn; gbv0 = gbn0; gbv1 = gbn1; }
        buf ^= 1;
    }
    // last tile
    do_mfma(buf ^ 1);

    // epilogue: C/D row = mt*16 + quad*4 + r, col = m; den in accd[r]
    const int ibase = i0 + mt * 16 + quad * 4;
    if (njc == 1) {
#pragma unroll
        for (int r = 0; r < 4; ++r) {
            const float rd = 1.0f / accd[r];
            float* dst = numout + (size_t)(ibase + r) * F_OUT + hh * D_HID + m;
            dst[0]  = acc0[r] * rd;
            dst[16] = acc1[r] * rd;
            dst[32] = acc2[r] * rd;
            dst[48] = acc3[r] * rd;
        }
    } else {
        float* nrow = numout + (size_t)jc * ((size_t)N_NODES * F_OUT);
#pragma unroll
        for (int r = 0; r < 4; ++r) {
            float* dst = nrow + (size_t)(ibase + r) * F_OUT + hh * D_HID + m;
            dst[0]  = acc0[r];
            dst[16] = acc1[r];
            dst[32] = acc2[r];
            dst[48] = acc3[r];
        }
        if (m == 0) {
#pragma unroll
            for (int r = 0; r < 4; ++r)
                den_g[((size_t)jc * N_NODES + ibase + r) * NUM_HEADS + hh] = accd[r];
        }
    }
}

// ---------------------------------------------------------------------------
// Kernel 3 (njc>1): sum chunk partials, divide, store f32.
// ---------------------------------------------------------------------------
__global__ __launch_bounds__(256) void reduce_kernel(
    const float* __restrict__ num, const float* __restrict__ den,
    float* __restrict__ out, int njc)
{
    const int idx = blockIdx.x * 256 + threadIdx.x;
    const int i  = idx >> 8;
    const int c  = idx & 255;
    const int hh = c >> 6;
    float n = 0.f, d = 0.f;
    for (int jc = 0; jc < njc; ++jc) {
        n += num[(size_t)jc * ((size_t)N_NODES * F_OUT) + idx];
        d += den[((size_t)jc * N_NODES + i) * NUM_HEADS + hh];
    }
    out[idx] = n / d;
}

// ---------------------------------------------------------------------------
extern "C" void kernel_launch(void* const* d_in, const int* in_sizes, int n_in,
                              void* d_out, int out_size, void* d_ws, size_t ws_size,
                              hipStream_t stream)
{
    const float* hmat = (const float*)d_in[0];   // (4096, 128) f32
    const float* adj  = (const float*)d_in[1];   // (4096, 4096) f32
    const float* Wp   = (const float*)d_in[2];   // (128, 256) f32
    const float* Wa   = (const float*)d_in[3];   // (128, 128) f32
    const float* watt = (const float*)d_in[4];   // (64,) f32
    float* out = (float*)d_out;                  // (4096, 256) f32

    char* ws = (char*)d_ws;
    bf16_t* GB  = (bf16_t*)ws;                                   // 2 MiB
    float*  el  = (float*)(ws + (2ull << 20));                   // 64 KiB
    float*  E1r = (float*)(ws + (2ull << 20) + (64ull << 10));   // 64 KiB
    float*  E2r = (float*)(ws + (2ull << 20) + (128ull << 10));  // 64 KiB
    const size_t baseoff = (2ull << 20) + (192ull << 10);

    const size_t num_bytes = (size_t)N_NODES * F_OUT * 4;        // 4 MiB per chunk
    const size_t den_bytes = (size_t)N_NODES * NUM_HEADS * 4;    // 64 KiB per chunk
    const int njc = (ws_size >= baseoff + 4 * (num_bytes + den_bytes)) ? 4 : 2;

    float* num = (float*)(ws + baseoff);
    float* den = (float*)(ws + baseoff + (size_t)njc * num_bytes);

    proj_kernel<<<1024, 384, 0, stream>>>(hmat, Wp, Wa, watt, GB, el, E1r, E2r);
    attn_kernel<<<dim3(64, njc), 1024, 0, stream>>>(adj, GB, el, E1r, E2r,
                                                    num, den, njc, (N_NODES / njc) / 64);
    reduce_kernel<<<(N_NODES * F_OUT) / 256, 256, 0, stream>>>(num, den, out, njc);
}

// Round 8
// 163.418 us; speedup vs baseline: 2.0480x; 1.0185x over previous
//
#include <hip/hip_runtime.h>
#include <hip/hip_bf16.h>

typedef __bf16 bf16_t;
typedef __bf16 bf16x4 __attribute__((ext_vector_type(4)));
typedef __bf16 bf16x8 __attribute__((ext_vector_type(8)));
typedef float floatx4 __attribute__((ext_vector_type(4)));

#define N_NODES 4096
#define F_IN 128
#define NUM_HEADS 4
#define D_HID 64
#define F_OUT 256  // NUM_HEADS * D_HID
#define NEG_SLOPE 0.2f

// ---------------------------------------------------------------------------
// Kernel 1: projections (f32 in; GB bf16 fragment-linear; el/E1r/E2r f32).
//   GB: g[j][h*64+f] stored so a 16x16x32 MFMA B-fragment is contiguous 1 KB:
//   GB[h][j>>5][f>>4][lane=(f&15)+16*((j>>3)&3)][j&7].
//   el[h][j]  = <ga[j,h,:], w_attn[:32]>
//   E1r[h][j] = exp(<ga[j,h,:], w_attn[32:]>),  E2r[h][j] = exp(0.2*<...>)
// 1024 blocks x 384 threads; block handles 4 nodes.
// ---------------------------------------------------------------------------
__global__ __launch_bounds__(384) void proj_kernel(
    const float* __restrict__ hmat, const float* __restrict__ Wp,
    const float* __restrict__ Wa, const float* __restrict__ wattn,
    bf16_t* __restrict__ GB, float* __restrict__ el,
    float* __restrict__ E1r, float* __restrict__ E2r)
{
    __shared__ float hl[4][F_IN];
    const int t = threadIdx.x;
    const int j0 = blockIdx.x * 4;

    if (t < 128) {
        const int jl = t >> 5, m0 = (t & 31) * 4;
        *reinterpret_cast<float4*>(&hl[jl][m0]) =
            *reinterpret_cast<const float4*>(&hmat[(size_t)(j0 + jl) * F_IN + m0]);
    }
    __syncthreads();

    float acc[4] = {0.f, 0.f, 0.f, 0.f};

    const float* wptr;
    int stride;
    if (t < 256) { wptr = Wp + t;         stride = 256; }
    else         { wptr = Wa + (t - 256); stride = 128; }

    for (int m = 0; m < F_IN; m += 4) {
        const float w0 = wptr[(size_t)(m + 0) * stride];
        const float w1 = wptr[(size_t)(m + 1) * stride];
        const float w2 = wptr[(size_t)(m + 2) * stride];
        const float w3 = wptr[(size_t)(m + 3) * stride];
#pragma unroll
        for (int jl = 0; jl < 4; ++jl) {
            const float4 hv = *reinterpret_cast<const float4*>(&hl[jl][m]);
            acc[jl] = fmaf(hv.w, w3, fmaf(hv.z, w2, fmaf(hv.y, w1, fmaf(hv.x, w0, acc[jl]))));
        }
    }

    if (t < 256) {
        const int h = t >> 6, f = t & 63;
        bf16x4 o;
#pragma unroll
        for (int q = 0; q < 4; ++q) o[q] = (bf16_t)acc[q];
        const size_t base = ((((size_t)h * 128 + (j0 >> 5)) * 4 + (f >> 4)) * 64
                             + (f & 15) + 16 * ((j0 >> 3) & 3)) * 8 + (j0 & 7);
        *reinterpret_cast<bf16x4*>(&GB[base]) = o;
    } else {
        const int ta = t - 256;          // waves 4,5; 32-lane group per head
        const int ha = ta >> 5, k = ta & 31;
        const float wl = wattn[k], wr = wattn[32 + k];
#pragma unroll
        for (int jl = 0; jl < 4; ++jl) {
            float vl = acc[jl] * wl;
            float vr = acc[jl] * wr;
#pragma unroll
            for (int s = 16; s >= 1; s >>= 1) {
                vl += __shfl_xor(vl, s, 64);
                vr += __shfl_xor(vr, s, 64);
            }
            if (k == 0) {
                el[ha * N_NODES + j0 + jl]  = vl;
                E1r[ha * N_NODES + j0 + jl] = __expf(vr);
                E2r[ha * N_NODES + j0 + jl] = __expf(NEG_SLOPE * vr);
            }
        }
    }
}

// ---------------------------------------------------------------------------
// Kernel 2: fused attention, register-resident A-fragments, no P/GB LDS.
// Grid (256 i-tiles of 16 rows, njc) x 256 threads = 4 waves (wave = head).
// Only adj goes through LDS (16x68 f32 tile, double-buffered, 1 barrier/tile;
// stride 68 floats -> uniform 8-phase b128 access, no excess conflicts).
// Lane l builds A-frag in regs: P(i0+(l&15), kt*32+quad*8+q) from adj_s +
// global E1r/E2r (L2, 4 lines/instr); B-frags are direct coalesced 1 KB
// global loads from fragment-linear GB (L2-resident). Den via ones-MFMA.
// LDS = 2*16*68*4 = 8704 B. __launch_bounds__(256,4) -> 128-VGPR cap.
// ---------------------------------------------------------------------------
__global__ __launch_bounds__(256, 4) void attn_kernel(
    const float* __restrict__ adj, const bf16_t* __restrict__ GB,
    const float* __restrict__ el, const float* __restrict__ E1r,
    const float* __restrict__ E2r,
    float* __restrict__ numout, float* __restrict__ den_g,
    int njc, int ntiles)
{
    __shared__ float adj_s[2][16 * 68];   // stride 68 floats per row

    const int tid = threadIdx.x;
    const int i0  = blockIdx.x * 16;
    const int jc  = blockIdx.y;
    const int jT0 = jc * ntiles * 64;

    // staging identity: thread -> (row r, 4-float col c)
    const int r = tid >> 4;               // 0..15
    const int c = tid & 15;               // 0..15 (x4 floats)

    // compute identity
    const int hh   = tid >> 6;            // wave = head
    const int lane = tid & 63;
    const int m    = lane & 15;           // A row / D col
    const int quad = lane >> 4;

    // i-side exponential factors (this wave's head only)
    const float eli = el[hh * N_NODES + i0 + m];
    const float E1i = __expf(eli);
    const float E2i = __expf(NEG_SLOPE * eli);
    const float Ti  = __expf(-eli);

    const float* adjp = adj + (size_t)(i0 + r) * N_NODES + c * 4;

    floatx4 acc0 = {0.f, 0.f, 0.f, 0.f};
    floatx4 acc1 = acc0, acc2 = acc0, acc3 = acc0, accd = acc0;
    bf16x8 ones;
#pragma unroll
    for (int q = 0; q < 8; ++q) ones[q] = (bf16_t)1.0f;

    // prologue: tile 0 staged, tile 1 prefetched
    float4 adjv = *reinterpret_cast<const float4*>(adjp + jT0);
    *reinterpret_cast<float4*>(&adj_s[0][r * 68 + c * 4]) = adjv;
    if (ntiles > 1)
        adjv = *reinterpret_cast<const float4*>(adjp + jT0 + 64);
    __syncthreads();

    for (int k = 0; k < ntiles; ++k) {
        const int buf = k & 1;
        const int jT  = jT0 + k * 64;

        if (k + 1 < ntiles) {
            *reinterpret_cast<float4*>(&adj_s[buf ^ 1][r * 68 + c * 4]) = adjv;
            if (k + 2 < ntiles)
                adjv = *reinterpret_cast<const float4*>(adjp + jT + 128);
        }

        const float*  E1p = E1r + hh * N_NODES + jT + quad * 8;
        const float*  E2p = E2r + hh * N_NODES + jT + quad * 8;
        const bf16_t* gbb = GB + (size_t)(hh * 128 + (jT >> 5)) * 2048 + lane * 8;

#pragma unroll
        for (int kt = 0; kt < 2; ++kt) {
            const float4 e1a = *reinterpret_cast<const float4*>(E1p + kt * 32);
            const float4 e1b = *reinterpret_cast<const float4*>(E1p + kt * 32 + 4);
            const float4 e2a = *reinterpret_cast<const float4*>(E2p + kt * 32);
            const float4 e2b = *reinterpret_cast<const float4*>(E2p + kt * 32 + 4);
            const float4 aa  = *reinterpret_cast<const float4*>(
                &adj_s[buf][m * 68 + kt * 32 + quad * 8]);
            const float4 ab  = *reinterpret_cast<const float4*>(
                &adj_s[buf][m * 68 + kt * 32 + quad * 8 + 4]);

            bf16x8 af;
            af[0] = (aa.x >= 0.5f) ? (bf16_t)((e1a.x > Ti) ? E1i * e1a.x : E2i * e2a.x) : (bf16_t)0.f;
            af[1] = (aa.y >= 0.5f) ? (bf16_t)((e1a.y > Ti) ? E1i * e1a.y : E2i * e2a.y) : (bf16_t)0.f;
            af[2] = (aa.z >= 0.5f) ? (bf16_t)((e1a.z > Ti) ? E1i * e1a.z : E2i * e2a.z) : (bf16_t)0.f;
            af[3] = (aa.w >= 0.5f) ? (bf16_t)((e1a.w > Ti) ? E1i * e1a.w : E2i * e2a.w) : (bf16_t)0.f;
            af[4] = (ab.x >= 0.5f) ? (bf16_t)((e1b.x > Ti) ? E1i * e1b.x : E2i * e2b.x) : (bf16_t)0.f;
            af[5] = (ab.y >= 0.5f) ? (bf16_t)((e1b.y > Ti) ? E1i * e1b.y : E2i * e2b.y) : (bf16_t)0.f;
            af[6] = (ab.z >= 0.5f) ? (bf16_t)((e1b.z > Ti) ? E1i * e1b.z : E2i * e2b.z) : (bf16_t)0.f;
            af[7] = (ab.w >= 0.5f) ? (bf16_t)((e1b.w > Ti) ? E1i * e1b.w : E2i * e2b.w) : (bf16_t)0.f;

            const bf16x8 b0 = *reinterpret_cast<const bf16x8*>(gbb + kt * 2048);
            const bf16x8 b1 = *reinterpret_cast<const bf16x8*>(gbb + kt * 2048 + 512);
            const bf16x8 b2 = *reinterpret_cast<const bf16x8*>(gbb + kt * 2048 + 1024);
            const bf16x8 b3 = *reinterpret_cast<const bf16x8*>(gbb + kt * 2048 + 1536);

            accd = __builtin_amdgcn_mfma_f32_16x16x32_bf16(af, ones, accd, 0, 0, 0);
            acc0 = __builtin_amdgcn_mfma_f32_16x16x32_bf16(af, b0, acc0, 0, 0, 0);
            acc1 = __builtin_amdgcn_mfma_f32_16x16x32_bf16(af, b1, acc1, 0, 0, 0);
            acc2 = __builtin_amdgcn_mfma_f32_16x16x32_bf16(af, b2, acc2, 0, 0, 0);
            acc3 = __builtin_amdgcn_mfma_f32_16x16x32_bf16(af, b3, acc3, 0, 0, 0);
        }
        __syncthreads();   // tile k reads done; tile k+1 stores published
    }

    // epilogue: C/D row = quad*4 + r, col = m; den replicated in accd[r]
    const int ibase = i0 + quad * 4;
    if (njc == 1) {
#pragma unroll
        for (int rr = 0; rr < 4; ++rr) {
            const float rd = 1.0f / accd[rr];
            float* dst = numout + (size_t)(ibase + rr) * F_OUT + hh * D_HID + m;
            dst[0]  = acc0[rr] * rd;
            dst[16] = acc1[rr] * rd;
            dst[32] = acc2[rr] * rd;
            dst[48] = acc3[rr] * rd;
        }
    } else {
        float* nrow = numout + (size_t)jc * ((size_t)N_NODES * F_OUT);
#pragma unroll
        for (int rr = 0; rr < 4; ++rr) {
            float* dst = nrow + (size_t)(ibase + rr) * F_OUT + hh * D_HID + m;
            dst[0]  = acc0[rr];
            dst[16] = acc1[rr];
            dst[32] = acc2[rr];
            dst[48] = acc3[rr];
        }
        if (m == 0) {
#pragma unroll
            for (int rr = 0; rr < 4; ++rr)
                den_g[((size_t)jc * N_NODES + ibase + rr) * NUM_HEADS + hh] = accd[rr];
        }
    }
}

// ---------------------------------------------------------------------------
// Kernel 3 (njc>1): sum chunk partials, divide, store f32.
// ---------------------------------------------------------------------------
__global__ __launch_bounds__(256) void reduce_kernel(
    const float* __restrict__ num, const float* __restrict__ den,
    float* __restrict__ out, int njc)
{
    const int idx = blockIdx.x * 256 + threadIdx.x;
    const int i  = idx >> 8;
    const int c  = idx & 255;
    const int hh = c >> 6;
    float n = 0.f, d = 0.f;
    for (int jc = 0; jc < njc; ++jc) {
        n += num[(size_t)jc * ((size_t)N_NODES * F_OUT) + idx];
        d += den[((size_t)jc * N_NODES + i) * NUM_HEADS + hh];
    }
    out[idx] = n / d;
}

// ---------------------------------------------------------------------------
extern "C" void kernel_launch(void* const* d_in, const int* in_sizes, int n_in,
                              void* d_out, int out_size, void* d_ws, size_t ws_size,
                              hipStream_t stream)
{
    const float* hmat = (const float*)d_in[0];   // (4096, 128) f32
    const float* adj  = (const float*)d_in[1];   // (4096, 4096) f32
    const float* Wp   = (const float*)d_in[2];   // (128, 256) f32
    const float* Wa   = (const float*)d_in[3];   // (128, 128) f32
    const float* watt = (const float*)d_in[4];   // (64,) f32
    float* out = (float*)d_out;                  // (4096, 256) f32

    char* ws = (char*)d_ws;
    bf16_t* GB  = (bf16_t*)ws;                                   // 2 MiB
    float*  el  = (float*)(ws + (2ull << 20));                   // 64 KiB
    float*  E1r = (float*)(ws + (2ull << 20) + (64ull << 10));   // 64 KiB
    float*  E2r = (float*)(ws + (2ull << 20) + (128ull << 10));  // 64 KiB
    const size_t baseoff = (2ull << 20) + (192ull << 10);

    const size_t num_bytes = (size_t)N_NODES * F_OUT * 4;        // 4 MiB per chunk
    const size_t den_bytes = (size_t)N_NODES * NUM_HEADS * 4;    // 64 KiB per chunk
    const int njc = (ws_size >= baseoff + 4 * (num_bytes + den_bytes)) ? 4 : 2;

    float* num = (float*)(ws + baseoff);
    float* den = (float*)(ws + baseoff + (size_t)njc * num_bytes);

    proj_kernel<<<1024, 384, 0, stream>>>(hmat, Wp, Wa, watt, GB, el, E1r, E2r);
    attn_kernel<<<dim3(256, njc), 256, 0, stream>>>(adj, GB, el, E1r, E2r,
                                                    num, den, njc, (N_NODES / njc) / 64);
    reduce_kernel<<<(N_NODES * F_OUT) / 256, 256, 0, stream>>>(num, den, out, njc);
}